// Round 9
// baseline (1372.846 us; speedup 1.0000x reference)
//
#include <hip/hip_runtime.h>
#include <hip/hip_bf16.h>
#include <math.h>

// Problem dims (fixed by reference)
#define B 32
#define S 256
#define H 768
#define KG 200
#define KGP 224      // KG padded to x32
#define FF 3072
#define LH 128
#define D 968        // H + KG
#define DP 1024      // D padded to multiple of 32
#define NT 11
#define G4 512       // 4*LH
#define START_TAG 9
#define END_TAG 10
#define M_TOK 8192   // B*S
#define L2E 1.4426950408889634f

typedef __attribute__((ext_vector_type(8))) short short8;
typedef __attribute__((ext_vector_type(4))) float f32x4;

// ---------------------------------------------------------------------------
__device__ __forceinline__ void gl_lds16(const void* gptr, void* lptr) {
    __builtin_amdgcn_global_load_lds(
        (const __attribute__((address_space(1))) void*)gptr,
        (__attribute__((address_space(3))) void*)lptr,
        16, 0, 0);
}

// LDS-only barrier (lgkmcnt(0); vmcnt/expcnt unconstrained).
__device__ __forceinline__ void barrier_lds() {
    __builtin_amdgcn_sched_barrier(0);
    __builtin_amdgcn_s_waitcnt(0xC07F);
    __builtin_amdgcn_s_barrier();
    __builtin_amdgcn_sched_barrier(0);
}

__device__ __forceinline__ float frcp(float x) { return __builtin_amdgcn_rcpf(x); }

// exp2f maps to v_exp_f32
__device__ __forceinline__ float e2(float x) { return exp2f(x); }

__device__ __forceinline__ float fsigmoid(float x) {   // for non-LSTM uses
    return frcp(1.f + __expf(-x));
}
__device__ __forceinline__ float ftanh(float x) {
    return 1.f - 2.f * frcp(__expf(2.f * x) + 1.f);
}

// ---------------------------------------------------------------------------
// kg slice cast: Akg (M_TOK, KGP) bf16 from in_emb cols H..D, zero pad.
__global__ __launch_bounds__(256) void castpad_kg_kernel(
    const float* __restrict__ in, __hip_bfloat16* __restrict__ Akg)
{
    size_t idx = (size_t)blockIdx.x * 256 + threadIdx.x;
    if (idx >= (size_t)M_TOK * KGP) return;
    int k = (int)(idx % KGP);
    size_t tok = idx / KGP;
    float v = (k < KG) ? in[tok * D + H + k] : 0.f;
    Akg[idx] = __float2bfloat16(v);
}

// ---------------------------------------------------------------------------
// LayerNorm + tanh + W2-dot per token; one wave per token (h in bf16).
__global__ __launch_bounds__(256) void ln_score_kernel(
    const __hip_bfloat16* __restrict__ h16,    // (M_TOK, H)
    const float* __restrict__ ln_g, const float* __restrict__ ln_b,
    const float* __restrict__ W2, const float* __restrict__ b2,
    float* __restrict__ scores)
{
    int wave = threadIdx.x >> 6, lane = threadIdx.x & 63;
    int tok = blockIdx.x * 4 + wave;
    const __hip_bfloat16* hp = h16 + (size_t)tok * H;
    float v[12], s1 = 0.f, s2 = 0.f;
#pragma unroll
    for (int i = 0; i < 12; ++i) {
        v[i] = __bfloat162float(hp[i * 64 + lane]);
        s1 += v[i]; s2 += v[i] * v[i];
    }
#pragma unroll
    for (int o = 32; o > 0; o >>= 1) {
        s1 += __shfl_xor(s1, o, 64);
        s2 += __shfl_xor(s2, o, 64);
    }
    float mu = s1 * (1.f / H);
    float var = s2 * (1.f / H) - mu * mu;
    float rstd = rsqrtf(var + 1e-5f);
    float sc = 0.f;
#pragma unroll
    for (int i = 0; i < 12; ++i) {
        int cidx = i * 64 + lane;
        sc += ftanh((v[i] - mu) * rstd * ln_g[cidx] + ln_b[cidx]) * W2[cidx];
    }
#pragma unroll
    for (int o = 32; o > 0; o >>= 1) sc += __shfl_xor(sc, o, 64);
    if (lane == 0) scores[tok] = sc + b2[0];
}

// ---------------------------------------------------------------------------
__global__ __launch_bounds__(256) void softmax_kernel(
    const float* __restrict__ scores, float* __restrict__ attw)
{
    int b = blockIdx.x, tid = threadIdx.x;
    __shared__ float red[256];
    float v = scores[b * S + tid];
    red[tid] = v; __syncthreads();
    for (int st = 128; st > 0; st >>= 1) {
        if (tid < st) red[tid] = fmaxf(red[tid], red[tid + st]);
        __syncthreads();
    }
    float m = red[0]; __syncthreads();
    float e = expf(v - m);
    red[tid] = e; __syncthreads();
    for (int st = 128; st > 0; st >>= 1) {
        if (tid < st) red[tid] += red[tid + st];
        __syncthreads();
    }
    attw[b * S + tid] = e / red[0];
}

// ---------------------------------------------------------------------------
// combined = [bert, kg*(1+attw)] -> bf16 K-padded only (residual read later
// from this same bf16 buffer).
__global__ __launch_bounds__(256) void combine2_kernel(
    const float* __restrict__ in, const float* __restrict__ attw,
    __hip_bfloat16* __restrict__ Ab)
{
    size_t idx = (size_t)blockIdx.x * 256 + threadIdx.x;   // over M_TOK*DP
    if (idx >= (size_t)M_TOK * DP) return;
    int d = (int)(idx & (DP - 1));
    size_t tok = idx >> 10;
    float v = 0.f;
    if (d < D) {
        v = in[tok * D + d];
        if (d >= H) v *= (1.f + attw[tok]);
    }
    Ab[idx] = __float2bfloat16(v);
}

// ---------------------------------------------------------------------------
// Weight cast: src (N,K) fp32 -> dst (Np,Kp) bf16, zero pad.
// gscale != 0: scale row n by SG[(n>>7)&3] (LSTM gate exp2-prescale).
__global__ __launch_bounds__(256) void castpad2d_kernel(
    const float* __restrict__ src, __hip_bfloat16* __restrict__ dst,
    int N, int K, int Np, int Kp, int gscale)
{
    size_t idx = (size_t)blockIdx.x * 256 + threadIdx.x;
    if (idx >= (size_t)Np * Kp) return;
    int n = (int)(idx / Kp), k = (int)(idx % Kp);
    float v = (n < N && k < K) ? src[(size_t)n * K + k] : 0.f;
    if (gscale) {
        const float SG[4] = { -L2E, -L2E, 2.f * L2E, -L2E };
        v *= SG[(n >> 7) & 3];
    }
    dst[idx] = __float2bfloat16(v);
}

// ---------------------------------------------------------------------------
// One-shot prep: 4 Whh casts (gate-scaled), stacked scaled biases, cls pad,
// kg_W1 pad. Grid-strided over segment table.
#define SEG_WHH 65536
__global__ __launch_bounds__(256) void prep_misc_kernel(
    const float* __restrict__ Whh0f, const float* __restrict__ Whh0b,
    const float* __restrict__ Whh1f, const float* __restrict__ Whh1b,
    const float* __restrict__ b0f, const float* __restrict__ b0b,
    const float* __restrict__ b1f, const float* __restrict__ b1b,
    const float* __restrict__ cls_W, const float* __restrict__ kg_W1,
    __hip_bfloat16* __restrict__ Whb0f, __hip_bfloat16* __restrict__ Whb0b,
    __hip_bfloat16* __restrict__ Whb1f, __hip_bfloat16* __restrict__ Whb1b,
    float* __restrict__ sb0, float* __restrict__ sb1,
    __hip_bfloat16* __restrict__ Wbcls, __hip_bfloat16* __restrict__ Wbkg1)
{
    const float SG[4] = { -L2E, -L2E, 2.f * L2E, -L2E };
    size_t idx = (size_t)blockIdx.x * 256 + threadIdx.x;
    // segments: 4*65536 whh | 1024 sb0 | 1024 sb1 | 32768 cls | 172032 kg
    if (idx < 4 * SEG_WHH) {
        int seg = (int)(idx >> 16), i = (int)(idx & (SEG_WHH - 1));
        float s = SG[i >> 14];
        const float* srcs[4] = { Whh0f, Whh0b, Whh1f, Whh1b };
        __hip_bfloat16* dsts[4] = { Whb0f, Whb0b, Whb1f, Whb1b };
        dsts[seg][i] = __float2bfloat16(srcs[seg][i] * s);
        return;
    }
    idx -= 4 * SEG_WHH;
    if (idx < 1024) {
        int n = (int)idx;
        float v = (n < 512) ? b0f[n] : b0b[n - 512];
        sb0[n] = v * SG[(n >> 7) & 3];
        return;
    }
    idx -= 1024;
    if (idx < 1024) {
        int n = (int)idx;
        float v = (n < 512) ? b1f[n] : b1b[n - 512];
        sb1[n] = v * SG[(n >> 7) & 3];
        return;
    }
    idx -= 1024;
    if (idx < 32768) {
        int n = (int)(idx >> 8), k = (int)(idx & 255);
        Wbcls[idx] = __float2bfloat16(n < NT ? cls_W[n * 256 + k] : 0.f);
        return;
    }
    idx -= 32768;
    if (idx < (size_t)H * KGP) {
        int n = (int)(idx / KGP), k = (int)(idx % KGP);
        Wbkg1[idx] = __float2bfloat16(k < KG ? kg_W1[(size_t)n * KG + k] : 0.f);
    }
}
#define PREP_TOTAL (4 * SEG_WHH + 1024 + 1024 + 32768 + H * KGP)

// ---------------------------------------------------------------------------
// bf16 MFMA GEMM: C(M,Np) = act(A(M,Kp) @ W(Np,Kp)^T + bias) [+ res].
// flags: bit0 relu; bit1 bf16 out; bit2 LSTM gate-interleave fp32 store
//   C[m*512 + (n&127)*4 + ((n>>7)&3) + (n>>9)*half_stride] (fwd/bwd stacked);
// bit3 compact fp32 store stride N_real; bit4 res is bf16 (stride res_ld).
__global__ __launch_bounds__(256) void mfma_gemm(
    const __hip_bfloat16* __restrict__ A,
    const __hip_bfloat16* __restrict__ Wb,
    const float* __restrict__ bias,
    const void* __restrict__ res, int res_ld, size_t half_stride,
    void* __restrict__ Cout,
    int Np, int Kp, int N_real, int flags)
{
    __shared__ short As[128 * 32];
    __shared__ short Bs[128 * 32];
    const int tid  = threadIdx.x;
    const int wave = tid >> 6;
    const int lane = tid & 63;
    const int bm = blockIdx.y * 128, bn = blockIdx.x * 128;
    const int sr = lane >> 2;
    const int sc = (lane & 3) * 8;
    const int fr = lane & 15;
    const int fq = lane >> 4;
    const int wm = (wave >> 1) * 64, wn = (wave & 1) * 64;

    f32x4 acc[4][4];
#pragma unroll
    for (int i = 0; i < 4; ++i)
#pragma unroll
        for (int j = 0; j < 4; ++j) acc[i][j] = (f32x4){0.f, 0.f, 0.f, 0.f};

    const __hip_bfloat16* ga0 = A  + (size_t)(bm + wave * 32      + sr) * Kp + sc;
    const __hip_bfloat16* ga1 = A  + (size_t)(bm + wave * 32 + 16 + sr) * Kp + sc;
    const __hip_bfloat16* gb0 = Wb + (size_t)(bn + wave * 32      + sr) * Kp + sc;
    const __hip_bfloat16* gb1 = Wb + (size_t)(bn + wave * 32 + 16 + sr) * Kp + sc;
    short* lA0 = &As[(wave * 2 + 0) * 512];
    short* lA1 = &As[(wave * 2 + 1) * 512];
    short* lB0 = &Bs[(wave * 2 + 0) * 512];
    short* lB1 = &Bs[(wave * 2 + 1) * 512];

    for (int k0 = 0; k0 < Kp; k0 += 32) {
        gl_lds16(ga0 + k0, lA0);
        gl_lds16(ga1 + k0, lA1);
        gl_lds16(gb0 + k0, lB0);
        gl_lds16(gb1 + k0, lB1);
        __syncthreads();

        short8 af[4], bfr[4];
#pragma unroll
        for (int mi = 0; mi < 4; ++mi)
            af[mi] = *(const short8*)&As[(wm + mi * 16 + fr) * 32 + fq * 8];
#pragma unroll
        for (int ni = 0; ni < 4; ++ni)
            bfr[ni] = *(const short8*)&Bs[(wn + ni * 16 + fr) * 32 + fq * 8];
#pragma unroll
        for (int mi = 0; mi < 4; ++mi)
#pragma unroll
            for (int ni = 0; ni < 4; ++ni)
                acc[mi][ni] = __builtin_amdgcn_mfma_f32_16x16x32_bf16(
                    af[mi], bfr[ni], acc[mi][ni], 0, 0, 0);
        __syncthreads();
    }

    const bool relu = flags & 1;
    const bool obf  = flags & 2;
    const bool gate = flags & 4;
    const bool cmp  = flags & 8;
    const bool rbf  = flags & 16;
#pragma unroll
    for (int mi = 0; mi < 4; ++mi) {
#pragma unroll
        for (int ni = 0; ni < 4; ++ni) {
#pragma unroll
            for (int r = 0; r < 4; ++r) {
                int m = bm + wm + mi * 16 + fq * 4 + r;
                int n = bn + wn + ni * 16 + fr;
                float v = acc[mi][ni][r];
                if (n < N_real) {
                    v += bias[n];
                    if (relu) v = fmaxf(v, 0.f);
                    if (res) {
                        if (rbf)
                            v += __bfloat162float(
                                ((const __hip_bfloat16*)res)[(size_t)m * res_ld + n]);
                        else
                            v += ((const float*)res)[(size_t)m * res_ld + n];
                    }
                } else {
                    v = 0.f;
                }
                if (gate) {
                    ((float*)Cout)[(size_t)m * 512 + ((n & 127) << 2)
                                   + ((n >> 7) & 3) + (size_t)(n >> 9) * half_stride] = v;
                } else if (cmp) {
                    if (n < N_real)
                        ((float*)Cout)[(size_t)m * N_real + n] = v;
                } else if (obf) {
                    ((__hip_bfloat16*)Cout)[(size_t)m * Np + n] = __float2bfloat16(v);
                } else {
                    ((float*)Cout)[(size_t)m * Np + n] = v;
                }
            }
        }
    }
}

// ---------------------------------------------------------------------------
// Batched MFMA LSTM recurrence, 1024 threads (16 waves = 4/SIMD).
// Gate pre-activations arrive PRE-SCALED for exp2: i,f,o by -log2e, g by
// +2*log2e (folded into Wih/Whh/bias at cast time). Gate math uses
// 5 exp2 + 3 rcp per h (shared denominators) instead of 5 exp + 5 rcp.
__global__ __launch_bounds__(1024, 4) void lstm_mfma_kernel(
    const float* __restrict__ pre_f, const float* __restrict__ pre_b,
    const __hip_bfloat16* __restrict__ whh_f,
    const __hip_bfloat16* __restrict__ whh_b,
    void* __restrict__ out, int out_bf16)   // out: (B,S,2*LH)
{
    const int dir = blockIdx.x >> 1;
    const int s0  = (blockIdx.x & 1) * 16;
    const float* pre = dir ? pre_b : pre_f;
    const __hip_bfloat16* whh = dir ? whh_b : whh_f;

    const int tid  = threadIdx.x;
    const int w16  = tid >> 6;
    const int grp  = w16 >> 3;
    const int w8   = w16 & 7;
    const int lane = tid & 63;
    const int l15  = lane & 15;
    const int q    = lane >> 4;
    const int col  = 16 * w8 + l15;
    const int r0   = grp * 2;

    short8 bf[4][4];
#pragma unroll
    for (int t = 0; t < 4; ++t) {
        const __hip_bfloat16* wrow = whh + (size_t)(t * 128 + col) * LH;
#pragma unroll
        for (int kt = 0; kt < 4; ++kt)
            bf[t][kt] = *(const short8*)(wrow + kt * 32 + q * 8);
    }

    __shared__ __hip_bfloat16 h_lds[2][16][136];
    for (int i = tid; i < 2 * 16 * 136; i += 1024)
        ((__hip_bfloat16*)h_lds)[i] = __float2bfloat16(0.f);

    float c0 = 0.f, c1 = 0.f;

    const float* pp0 = pre + ((size_t)(s0 + 4 * q + r0    ) * S + (dir ? (S - 1) : 0)) * G4 + col * 4;
    const float* pp1 = pre + ((size_t)(s0 + 4 * q + r0 + 1) * S + (dir ? (S - 1) : 0)) * G4 + col * 4;
    const int stepoff = dir ? -G4 : G4;

    float4 pc0 = *(const float4*)pp0;
    float4 pc1 = *(const float4*)pp1;

    barrier_lds();
    int p = 0;

    for (int step = 0; step < S; ++step) {
        float4 pn0 = make_float4(0.f, 0.f, 0.f, 0.f);
        float4 pn1 = pn0;
        if (step + 1 < S) {
            pp0 += stepoff; pp1 += stepoff;
            pn0 = *(const float4*)pp0;
            pn1 = *(const float4*)pp1;
        }

        short8 af[4];
#pragma unroll
        for (int kt = 0; kt < 4; ++kt)
            af[kt] = *(const short8*)&h_lds[p][l15][kt * 32 + q * 8];

        f32x4 acc[4];
#pragma unroll
        for (int t = 0; t < 4; ++t) {
            acc[t] = (f32x4){0.f, 0.f, 0.f, 0.f};
#pragma unroll
            for (int kt = 0; kt < 4; ++kt)
                acc[t] = __builtin_amdgcn_mfma_f32_16x16x32_bf16(
                    af[kt], bf[t][kt], acc[t], 0, 0, 0);
        }

        float a0[4], a1[4];
#pragma unroll
        for (int t = 0; t < 4; ++t) {
            a0[t] = grp ? acc[t][2] : acc[t][0];
            a1[t] = grp ? acc[t][3] : acc[t][1];
        }

        const int tcur = dir ? (S - 1 - step) : step;

        // h0 ---------------------------------------------------------------
        float Ei = e2(a0[0] + pc0.x);                 // e^{-i}
        float Ef = e2(a0[1] + pc0.y);                 // e^{-f}
        float Eg = e2(fminf(a0[2] + pc0.z, 80.f));    // e^{2g}
        float Eo = e2(a0[3] + pc0.w);                 // e^{-o}
        float T  = (Eg - 1.f) * frcp((1.f + Ei) * (Eg + 1.f));  // sig(i)tanh(g)
        c0 = fmaf(c0, frcp(1.f + Ef), T);
        float E2 = e2(fminf(c0 * (2.f * L2E), 80.f)); // e^{2c}
        float h0 = (E2 - 1.f) * frcp((1.f + Eo) * (E2 + 1.f));  // sig(o)tanh(c)

        // h1 ---------------------------------------------------------------
        Ei = e2(a1[0] + pc1.x);
        Ef = e2(a1[1] + pc1.y);
        Eg = e2(fminf(a1[2] + pc1.z, 80.f));
        Eo = e2(a1[3] + pc1.w);
        T  = (Eg - 1.f) * frcp((1.f + Ei) * (Eg + 1.f));
        c1 = fmaf(c1, frcp(1.f + Ef), T);
        E2 = e2(fminf(c1 * (2.f * L2E), 80.f));
        float h1 = (E2 - 1.f) * frcp((1.f + Eo) * (E2 + 1.f));

        __hip_bfloat16 hb0 = __float2bfloat16(h0);
        __hip_bfloat16 hb1 = __float2bfloat16(h1);
        h_lds[p ^ 1][4 * q + r0    ][col] = hb0;
        h_lds[p ^ 1][4 * q + r0 + 1][col] = hb1;

        size_t tok0 = (size_t)(s0 + 4 * q + r0    ) * S + tcur;
        size_t tok1 = (size_t)(s0 + 4 * q + r0 + 1) * S + tcur;
        if (out_bf16) {
            ((__hip_bfloat16*)out)[tok0 * 256 + dir * 128 + col] = hb0;
            ((__hip_bfloat16*)out)[tok1 * 256 + dir * 128 + col] = hb1;
        } else {
            ((float*)out)[tok0 * 256 + dir * 128 + col] = h0;
            ((float*)out)[tok1 * 256 + dir * 128 + col] = h1;
        }
        barrier_lds();
        p ^= 1;
        pc0 = pn0; pc1 = pn1;
    }
}

// ---------------------------------------------------------------------------
// CRF NLL per sample (em/mask prefetched one step ahead)
__global__ __launch_bounds__(64) void crf_kernel(
    const float* __restrict__ em, const int* __restrict__ labels,
    const int* __restrict__ mask, const float* __restrict__ trans,
    float* __restrict__ nll)
{
    int b = blockIdx.x, tid = threadIdx.x;
    __shared__ float tr[NT * NT];
    __shared__ float alpha[NT];
    __shared__ float red[64];
    __shared__ float gold_s;

    for (int i = tid; i < NT * NT; i += 64) tr[i] = trans[i];
    __syncthreads();

    float emit = 0.f, pair = 0.f, lenf = 0.f;
    for (int s = tid; s < S; s += 64) {
        int lab = labels[b * S + s];
        float mf = (float)mask[b * S + s];
        emit += em[(size_t)(b * S + s) * NT + lab] * mf;
        lenf += mf;
        if (s >= 1) {
            int lp = labels[b * S + s - 1];
            pair += tr[lp * NT + lab] * mf;
        }
    }
    red[tid] = emit; __syncthreads();
    for (int st = 32; st > 0; st >>= 1) { if (tid < st) red[tid] += red[tid + st]; __syncthreads(); }
    float emit_tot = red[0]; __syncthreads();
    red[tid] = pair; __syncthreads();
    for (int st = 32; st > 0; st >>= 1) { if (tid < st) red[tid] += red[tid + st]; __syncthreads(); }
    float pair_tot = red[0]; __syncthreads();
    red[tid] = lenf; __syncthreads();
    for (int st = 32; st > 0; st >>= 1) { if (tid < st) red[tid] += red[tid + st]; __syncthreads(); }
    float len_tot = red[0]; __syncthreads();

    if (tid == 0) {
        int len_i = (int)(len_tot + 0.5f);
        int last = labels[b * S + len_i - 1];
        gold_s = tr[START_TAG * NT + labels[b * S]] + emit_tot + pair_tot
               + tr[last * NT + END_TAG];
    }
    if (tid < NT) alpha[tid] = tr[START_TAG * NT + tid] + em[(size_t)(b * S) * NT + tid];
    __syncthreads();

    float ecur = (tid < NT) ? em[(size_t)(b * S + 1) * NT + tid] : 0.f;
    int   mcur = mask[b * S + 1];

    for (int t = 1; t < S; ++t) {
        // prefetch t+1
        float enxt = 0.f; int mnxt = 0;
        if (t + 1 < S) {
            if (tid < NT) enxt = em[(size_t)(b * S + t + 1) * NT + tid];
            mnxt = mask[b * S + t + 1];
        }
        float newv = 0.f;
        if (tid < NT) {
            float vals[NT];
            float m = -1e30f;
#pragma unroll
            for (int i2 = 0; i2 < NT; ++i2) {
                float v = alpha[i2] + tr[i2 * NT + tid];
                vals[i2] = v;
                m = fmaxf(m, v);
            }
            float ssum = 0.f;
#pragma unroll
            for (int i2 = 0; i2 < NT; ++i2) ssum += __expf(vals[i2] - m);
            newv = m + __logf(ssum) + ecur;
            if (!(mcur > 0)) newv = alpha[tid];
        }
        __syncthreads();
        if (tid < NT) alpha[tid] = newv;
        __syncthreads();
        ecur = enxt; mcur = mnxt;
    }

    if (tid < NT) red[tid] = alpha[tid] + tr[tid * NT + END_TAG];
    __syncthreads();
    if (tid == 0) {
        float m = -1e30f;
        for (int j = 0; j < NT; ++j) m = fmaxf(m, red[j]);
        float ssum = 0.f;
        for (int j = 0; j < NT; ++j) ssum += __expf(red[j] - m);
        float logZ = m + __logf(ssum);
        nll[b] = logZ - gold_s;
    }
}

__global__ void mean_kernel(const float* __restrict__ nll, float* __restrict__ out)
{
    if (threadIdx.x == 0) {
        float s = 0.f;
        for (int i = 0; i < B; ++i) s += nll[i];
        out[0] = s / (float)B;
    }
}

// ---------------------------------------------------------------------------
extern "C" void kernel_launch(void* const* d_in, const int* in_sizes, int n_in,
                              void* d_out, int out_size, void* d_ws, size_t ws_size,
                              hipStream_t stream)
{
    const float* in_emb = (const float*)d_in[0];
    const int*   mask   = (const int*)d_in[1];
    const int*   labels = (const int*)d_in[2];
    const float* kg_W1  = (const float*)d_in[3];
    const float* kg_b1  = (const float*)d_in[4];
    const float* ln_g   = (const float*)d_in[5];
    const float* ln_b   = (const float*)d_in[6];
    const float* kg_W2  = (const float*)d_in[7];
    const float* kg_b2  = (const float*)d_in[8];
    const float* ff_W1  = (const float*)d_in[9];
    const float* ff_b1  = (const float*)d_in[10];
    const float* ff_W2  = (const float*)d_in[11];
    const float* ff_b2  = (const float*)d_in[12];
    const float* Wih0f  = (const float*)d_in[13];
    const float* Whh0f  = (const float*)d_in[14];
    const float* b0f    = (const float*)d_in[15];
    const float* Wih0b  = (const float*)d_in[16];
    const float* Whh0b  = (const float*)d_in[17];
    const float* b0b    = (const float*)d_in[18];
    const float* Wih1f  = (const float*)d_in[19];
    const float* Whh1f  = (const float*)d_in[20];
    const float* b1f    = (const float*)d_in[21];
    const float* Wih1b  = (const float*)d_in[22];
    const float* Whh1b  = (const float*)d_in[23];
    const float* b1b    = (const float*)d_in[24];
    const float* cls_W  = (const float*)d_in[25];
    const float* cls_b  = (const float*)d_in[26];
    const float* trans  = (const float*)d_in[27];
    (void)ws_size; (void)in_sizes; (void)n_in; (void)out_size;

    // ---- workspace arena ----
    char* wsb = (char*)d_ws;
    size_t o = 0;
    __hip_bfloat16* Ab     = (__hip_bfloat16*)(wsb + o);   size_t ab_off = o; o += (size_t)M_TOK * DP * 2;
    char*           big    = wsb + o;                      o += (size_t)M_TOK * FF * 2;
    __hip_bfloat16* xb     = (__hip_bfloat16*)(wsb + o);   o += (size_t)M_TOK * DP * 2;
    __hip_bfloat16* Wbff1  = (__hip_bfloat16*)(wsb + o);   o += (size_t)FF * DP * 2;
    __hip_bfloat16* Wbff2  = (__hip_bfloat16*)(wsb + o);   o += (size_t)DP * FF * 2;
    __hip_bfloat16* Wb0    = (__hip_bfloat16*)(wsb + o);   o += (size_t)1024 * DP * 2;   // stacked f|b
    __hip_bfloat16* Wb1    = (__hip_bfloat16*)(wsb + o);   o += (size_t)1024 * 256 * 2;  // stacked f|b
    __hip_bfloat16* Whb0f  = (__hip_bfloat16*)(wsb + o);   o += (size_t)G4 * LH * 2;
    __hip_bfloat16* Whb0b  = (__hip_bfloat16*)(wsb + o);   o += (size_t)G4 * LH * 2;
    __hip_bfloat16* Whb1f  = (__hip_bfloat16*)(wsb + o);   o += (size_t)G4 * LH * 2;
    __hip_bfloat16* Whb1b  = (__hip_bfloat16*)(wsb + o);   o += (size_t)G4 * LH * 2;
    __hip_bfloat16* Wbkg1  = (__hip_bfloat16*)(wsb + o);   o += (size_t)H * KGP * 2;
    __hip_bfloat16* Wbcls  = (__hip_bfloat16*)(wsb + o);   o += (size_t)128 * 256 * 2;
    float*          sb0    = (float*)(wsb + o);            o += 1024 * 4;
    float*          sb1    = (float*)(wsb + o);            o += 1024 * 4;
    float*          scores = (float*)(wsb + o);            o += (size_t)M_TOK * 4;
    float*          attw   = (float*)(wsb + o);            o += (size_t)M_TOK * 4;
    float*          emis   = (float*)(wsb + o);            o += (size_t)M_TOK * NT * 4;
    float*          nll    = (float*)(wsb + o);            o += B * 4;
    // big region reuse timeline:
    __hip_bfloat16* h16   = (__hip_bfloat16*)(big + 0);                // kg proj out (12.6MB)
    __hip_bfloat16* Akg   = (__hip_bfloat16*)(big + 33554432);         // kg bf16 in
    __hip_bfloat16* ff1b  = (__hip_bfloat16*)big;                      // FF1 out
    float*          pre0f = (float*)(big + 0);                         // after FF2
    float*          pre0b = (float*)(big + 16777216);
    __hip_bfloat16* x1b   = (__hip_bfloat16*)(big + 33554432);         // LSTM0 out
    float*          pre1f = (float*)(big + 0);                         // after LSTM0
    float*          pre1b = (float*)(big + 16777216);
    __hip_bfloat16* x2b   = (__hip_bfloat16*)(wsb + ab_off);           // LSTM1 out (reuse Ab)
    const size_t HALF_STRIDE = 4194304;                                // floats pre0f->pre0b

    // ---- weight prep ----
    castpad2d_kernel<<<(FF * DP + 255) / 256, 256, 0, stream>>>(ff_W1, Wbff1, FF, D,  FF, DP, 0);
    castpad2d_kernel<<<(DP * FF + 255) / 256, 256, 0, stream>>>(ff_W2, Wbff2, D,  FF, DP, FF, 0);
    // stacked + gate-scaled LSTM input weights
    castpad2d_kernel<<<(G4 * DP + 255) / 256, 256, 0, stream>>>(Wih0f, Wb0,            G4, D, G4, DP, 1);
    castpad2d_kernel<<<(G4 * DP + 255) / 256, 256, 0, stream>>>(Wih0b, Wb0 + 512 * DP, G4, D, G4, DP, 1);
    castpad2d_kernel<<<(G4 * 256 + 255) / 256, 256, 0, stream>>>(Wih1f, Wb1,             G4, 256, G4, 256, 1);
    castpad2d_kernel<<<(G4 * 256 + 255) / 256, 256, 0, stream>>>(Wih1b, Wb1 + 512 * 256, G4, 256, G4, 256, 1);
    prep_misc_kernel<<<(PREP_TOTAL + 255) / 256, 256, 0, stream>>>(
        Whh0f, Whh0b, Whh1f, Whh1b, b0f, b0b, b1f, b1b, cls_W, kg_W1,
        Whb0f, Whb0b, Whb1f, Whb1b, sb0, sb1, Wbcls, Wbkg1);

    // ---- attention front-end ----
    castpad_kg_kernel<<<(M_TOK * KGP + 255) / 256, 256, 0, stream>>>(in_emb, Akg);
    mfma_gemm<<<dim3(H / 128, M_TOK / 128), 256, 0, stream>>>(
        Akg, Wbkg1, kg_b1, nullptr, 0, 0, h16, H, KGP, H, 2);
    ln_score_kernel<<<M_TOK / 4, 256, 0, stream>>>(
        h16, ln_g, ln_b, kg_W2, kg_b2, scores);
    softmax_kernel<<<B, 256, 0, stream>>>(scores, attw);
    combine2_kernel<<<(M_TOK * DP + 255) / 256, 256, 0, stream>>>(in_emb, attw, Ab);

    // ---- FF block ----
    mfma_gemm<<<dim3(FF / 128, M_TOK / 128), 256, 0, stream>>>(
        Ab, Wbff1, ff_b1, nullptr, 0, 0, ff1b, FF, DP, FF, 1 | 2);
    mfma_gemm<<<dim3(DP / 128, M_TOK / 128), 256, 0, stream>>>(
        ff1b, Wbff2, ff_b2, Ab, DP, 0, xb, DP, FF, D, 2 | 16);

    // ---- LSTM layer 0 (stacked fwd+bwd pre GEMM, gate-interleaved) ----
    mfma_gemm<<<dim3(1024 / 128, M_TOK / 128), 256, 0, stream>>>(
        xb, Wb0, sb0, nullptr, 0, HALF_STRIDE, pre0f, 1024, DP, 1024, 4);
    lstm_mfma_kernel<<<4, 1024, 0, stream>>>(pre0f, pre0b, Whb0f, Whb0b, x1b, 1);

    // ---- LSTM layer 1 ----
    mfma_gemm<<<dim3(1024 / 128, M_TOK / 128), 256, 0, stream>>>(
        x1b, Wb1, sb1, nullptr, 0, HALF_STRIDE, pre1f, 1024, 256, 1024, 4);
    lstm_mfma_kernel<<<4, 1024, 0, stream>>>(pre1f, pre1b, Whb1f, Whb1b, x2b, 1);

    // ---- emissions + CRF + mean ----
    mfma_gemm<<<dim3(1, M_TOK / 128), 256, 0, stream>>>(
        x2b, Wbcls, cls_b, nullptr, 0, 0, emis, 128, 256, NT, 8);
    crf_kernel<<<B, 64, 0, stream>>>(emis, labels, mask, trans, nll);
    mean_kernel<<<1, 64, 0, stream>>>(nll, (float*)d_out);
}

// Round 10
// 1153.292 us; speedup vs baseline: 1.1904x; 1.1904x over previous
//
#include <hip/hip_runtime.h>
#include <hip/hip_bf16.h>
#include <math.h>

// Problem dims (fixed by reference)
#define B 32
#define S 256
#define H 768
#define KG 200
#define KGP 224      // KG padded to x32
#define FF 3072
#define LH 128
#define D 968        // H + KG
#define DP 1024      // D padded to multiple of 32
#define NT 11
#define G4 512       // 4*LH
#define START_TAG 9
#define END_TAG 10
#define M_TOK 8192   // B*S
#define L2E 1.4426950408889634f

typedef __attribute__((ext_vector_type(8))) short short8;
typedef __attribute__((ext_vector_type(4))) float f32x4;

// ---------------------------------------------------------------------------
__device__ __forceinline__ void gl_lds16(const void* gptr, void* lptr) {
    __builtin_amdgcn_global_load_lds(
        (const __attribute__((address_space(1))) void*)gptr,
        (__attribute__((address_space(3))) void*)lptr,
        16, 0, 0);
}

// LDS-only barrier (lgkmcnt(0); vmcnt/expcnt unconstrained).
__device__ __forceinline__ void barrier_lds() {
    __builtin_amdgcn_sched_barrier(0);
    __builtin_amdgcn_s_waitcnt(0xC07F);
    __builtin_amdgcn_s_barrier();
    __builtin_amdgcn_sched_barrier(0);
}

__device__ __forceinline__ float frcp(float x) { return __builtin_amdgcn_rcpf(x); }

// RAW hardware v_exp_f32 (exp2). NOTE: exp2f() without -ffast-math lowers to
// __ocml_exp2_f32 (denorm-handling slow path, ~3x instructions) — that was
// round 9's regression. The builtin is the bare instruction.
__device__ __forceinline__ float e2(float x) { return __builtin_amdgcn_exp2f(x); }

__device__ __forceinline__ float fsigmoid(float x) {   // for non-LSTM uses
    return frcp(1.f + __expf(-x));
}
__device__ __forceinline__ float ftanh(float x) {
    return 1.f - 2.f * frcp(__expf(2.f * x) + 1.f);
}

// ---------------------------------------------------------------------------
// kg slice cast: Akg (M_TOK, KGP) bf16 from in_emb cols H..D, zero pad.
__global__ __launch_bounds__(256) void castpad_kg_kernel(
    const float* __restrict__ in, __hip_bfloat16* __restrict__ Akg)
{
    size_t idx = (size_t)blockIdx.x * 256 + threadIdx.x;
    if (idx >= (size_t)M_TOK * KGP) return;
    int k = (int)(idx % KGP);
    size_t tok = idx / KGP;
    float v = (k < KG) ? in[tok * D + H + k] : 0.f;
    Akg[idx] = __float2bfloat16(v);
}

// ---------------------------------------------------------------------------
// LayerNorm + tanh + W2-dot per token; one wave per token (h in bf16).
__global__ __launch_bounds__(256) void ln_score_kernel(
    const __hip_bfloat16* __restrict__ h16,    // (M_TOK, H)
    const float* __restrict__ ln_g, const float* __restrict__ ln_b,
    const float* __restrict__ W2, const float* __restrict__ b2,
    float* __restrict__ scores)
{
    int wave = threadIdx.x >> 6, lane = threadIdx.x & 63;
    int tok = blockIdx.x * 4 + wave;
    const __hip_bfloat16* hp = h16 + (size_t)tok * H;
    float v[12], s1 = 0.f, s2 = 0.f;
#pragma unroll
    for (int i = 0; i < 12; ++i) {
        v[i] = __bfloat162float(hp[i * 64 + lane]);
        s1 += v[i]; s2 += v[i] * v[i];
    }
#pragma unroll
    for (int o = 32; o > 0; o >>= 1) {
        s1 += __shfl_xor(s1, o, 64);
        s2 += __shfl_xor(s2, o, 64);
    }
    float mu = s1 * (1.f / H);
    float var = s2 * (1.f / H) - mu * mu;
    float rstd = rsqrtf(var + 1e-5f);
    float sc = 0.f;
#pragma unroll
    for (int i = 0; i < 12; ++i) {
        int cidx = i * 64 + lane;
        sc += ftanh((v[i] - mu) * rstd * ln_g[cidx] + ln_b[cidx]) * W2[cidx];
    }
#pragma unroll
    for (int o = 32; o > 0; o >>= 1) sc += __shfl_xor(sc, o, 64);
    if (lane == 0) scores[tok] = sc + b2[0];
}

// ---------------------------------------------------------------------------
__global__ __launch_bounds__(256) void softmax_kernel(
    const float* __restrict__ scores, float* __restrict__ attw)
{
    int b = blockIdx.x, tid = threadIdx.x;
    __shared__ float red[256];
    float v = scores[b * S + tid];
    red[tid] = v; __syncthreads();
    for (int st = 128; st > 0; st >>= 1) {
        if (tid < st) red[tid] = fmaxf(red[tid], red[tid + st]);
        __syncthreads();
    }
    float m = red[0]; __syncthreads();
    float e = expf(v - m);
    red[tid] = e; __syncthreads();
    for (int st = 128; st > 0; st >>= 1) {
        if (tid < st) red[tid] += red[tid + st];
        __syncthreads();
    }
    attw[b * S + tid] = e / red[0];
}

// ---------------------------------------------------------------------------
// combined = [bert, kg*(1+attw)] -> bf16 K-padded only (residual read later
// from this same bf16 buffer).
__global__ __launch_bounds__(256) void combine2_kernel(
    const float* __restrict__ in, const float* __restrict__ attw,
    __hip_bfloat16* __restrict__ Ab)
{
    size_t idx = (size_t)blockIdx.x * 256 + threadIdx.x;   // over M_TOK*DP
    if (idx >= (size_t)M_TOK * DP) return;
    int d = (int)(idx & (DP - 1));
    size_t tok = idx >> 10;
    float v = 0.f;
    if (d < D) {
        v = in[tok * D + d];
        if (d >= H) v *= (1.f + attw[tok]);
    }
    Ab[idx] = __float2bfloat16(v);
}

// ---------------------------------------------------------------------------
// Weight cast: src (N,K) fp32 -> dst (Np,Kp) bf16, zero pad.
// gscale != 0: scale row n by SG[(n>>7)&3] (LSTM gate exp2-prescale).
__global__ __launch_bounds__(256) void castpad2d_kernel(
    const float* __restrict__ src, __hip_bfloat16* __restrict__ dst,
    int N, int K, int Np, int Kp, int gscale)
{
    size_t idx = (size_t)blockIdx.x * 256 + threadIdx.x;
    if (idx >= (size_t)Np * Kp) return;
    int n = (int)(idx / Kp), k = (int)(idx % Kp);
    float v = (n < N && k < K) ? src[(size_t)n * K + k] : 0.f;
    if (gscale) {
        const float SG[4] = { -L2E, -L2E, 2.f * L2E, -L2E };
        v *= SG[(n >> 7) & 3];
    }
    dst[idx] = __float2bfloat16(v);
}

// ---------------------------------------------------------------------------
// One-shot prep: 4 Whh casts (gate-scaled), stacked scaled biases, cls pad,
// kg_W1 pad. Grid-strided over segment table.
#define SEG_WHH 65536
__global__ __launch_bounds__(256) void prep_misc_kernel(
    const float* __restrict__ Whh0f, const float* __restrict__ Whh0b,
    const float* __restrict__ Whh1f, const float* __restrict__ Whh1b,
    const float* __restrict__ b0f, const float* __restrict__ b0b,
    const float* __restrict__ b1f, const float* __restrict__ b1b,
    const float* __restrict__ cls_W, const float* __restrict__ kg_W1,
    __hip_bfloat16* __restrict__ Whb0f, __hip_bfloat16* __restrict__ Whb0b,
    __hip_bfloat16* __restrict__ Whb1f, __hip_bfloat16* __restrict__ Whb1b,
    float* __restrict__ sb0, float* __restrict__ sb1,
    __hip_bfloat16* __restrict__ Wbcls, __hip_bfloat16* __restrict__ Wbkg1)
{
    const float SG[4] = { -L2E, -L2E, 2.f * L2E, -L2E };
    size_t idx = (size_t)blockIdx.x * 256 + threadIdx.x;
    // segments: 4*65536 whh | 1024 sb0 | 1024 sb1 | 32768 cls | 172032 kg
    if (idx < 4 * SEG_WHH) {
        int seg = (int)(idx >> 16), i = (int)(idx & (SEG_WHH - 1));
        float s = SG[i >> 14];
        const float* srcs[4] = { Whh0f, Whh0b, Whh1f, Whh1b };
        __hip_bfloat16* dsts[4] = { Whb0f, Whb0b, Whb1f, Whb1b };
        dsts[seg][i] = __float2bfloat16(srcs[seg][i] * s);
        return;
    }
    idx -= 4 * SEG_WHH;
    if (idx < 1024) {
        int n = (int)idx;
        float v = (n < 512) ? b0f[n] : b0b[n - 512];
        sb0[n] = v * SG[(n >> 7) & 3];
        return;
    }
    idx -= 1024;
    if (idx < 1024) {
        int n = (int)idx;
        float v = (n < 512) ? b1f[n] : b1b[n - 512];
        sb1[n] = v * SG[(n >> 7) & 3];
        return;
    }
    idx -= 1024;
    if (idx < 32768) {
        int n = (int)(idx >> 8), k = (int)(idx & 255);
        Wbcls[idx] = __float2bfloat16(n < NT ? cls_W[n * 256 + k] : 0.f);
        return;
    }
    idx -= 32768;
    if (idx < (size_t)H * KGP) {
        int n = (int)(idx / KGP), k = (int)(idx % KGP);
        Wbkg1[idx] = __float2bfloat16(k < KG ? kg_W1[(size_t)n * KG + k] : 0.f);
    }
}
#define PREP_TOTAL (4 * SEG_WHH + 1024 + 1024 + 32768 + H * KGP)

// ---------------------------------------------------------------------------
// bf16 MFMA GEMM: C(M,Np) = act(A(M,Kp) @ W(Np,Kp)^T + bias) [+ res].
// flags: bit0 relu; bit1 bf16 out; bit2 LSTM gate-interleave fp32 store
//   C[m*512 + (n&127)*4 + ((n>>7)&3) + (n>>9)*half_stride] (fwd/bwd stacked);
// bit3 compact fp32 store stride N_real; bit4 res is bf16 (stride res_ld).
__global__ __launch_bounds__(256) void mfma_gemm(
    const __hip_bfloat16* __restrict__ A,
    const __hip_bfloat16* __restrict__ Wb,
    const float* __restrict__ bias,
    const void* __restrict__ res, int res_ld, size_t half_stride,
    void* __restrict__ Cout,
    int Np, int Kp, int N_real, int flags)
{
    __shared__ short As[128 * 32];
    __shared__ short Bs[128 * 32];
    const int tid  = threadIdx.x;
    const int wave = tid >> 6;
    const int lane = tid & 63;
    const int bm = blockIdx.y * 128, bn = blockIdx.x * 128;
    const int sr = lane >> 2;
    const int sc = (lane & 3) * 8;
    const int fr = lane & 15;
    const int fq = lane >> 4;
    const int wm = (wave >> 1) * 64, wn = (wave & 1) * 64;

    f32x4 acc[4][4];
#pragma unroll
    for (int i = 0; i < 4; ++i)
#pragma unroll
        for (int j = 0; j < 4; ++j) acc[i][j] = (f32x4){0.f, 0.f, 0.f, 0.f};

    const __hip_bfloat16* ga0 = A  + (size_t)(bm + wave * 32      + sr) * Kp + sc;
    const __hip_bfloat16* ga1 = A  + (size_t)(bm + wave * 32 + 16 + sr) * Kp + sc;
    const __hip_bfloat16* gb0 = Wb + (size_t)(bn + wave * 32      + sr) * Kp + sc;
    const __hip_bfloat16* gb1 = Wb + (size_t)(bn + wave * 32 + 16 + sr) * Kp + sc;
    short* lA0 = &As[(wave * 2 + 0) * 512];
    short* lA1 = &As[(wave * 2 + 1) * 512];
    short* lB0 = &Bs[(wave * 2 + 0) * 512];
    short* lB1 = &Bs[(wave * 2 + 1) * 512];

    for (int k0 = 0; k0 < Kp; k0 += 32) {
        gl_lds16(ga0 + k0, lA0);
        gl_lds16(ga1 + k0, lA1);
        gl_lds16(gb0 + k0, lB0);
        gl_lds16(gb1 + k0, lB1);
        __syncthreads();

        short8 af[4], bfr[4];
#pragma unroll
        for (int mi = 0; mi < 4; ++mi)
            af[mi] = *(const short8*)&As[(wm + mi * 16 + fr) * 32 + fq * 8];
#pragma unroll
        for (int ni = 0; ni < 4; ++ni)
            bfr[ni] = *(const short8*)&Bs[(wn + ni * 16 + fr) * 32 + fq * 8];
#pragma unroll
        for (int mi = 0; mi < 4; ++mi)
#pragma unroll
            for (int ni = 0; ni < 4; ++ni)
                acc[mi][ni] = __builtin_amdgcn_mfma_f32_16x16x32_bf16(
                    af[mi], bfr[ni], acc[mi][ni], 0, 0, 0);
        __syncthreads();
    }

    const bool relu = flags & 1;
    const bool obf  = flags & 2;
    const bool gate = flags & 4;
    const bool cmp  = flags & 8;
    const bool rbf  = flags & 16;
#pragma unroll
    for (int mi = 0; mi < 4; ++mi) {
#pragma unroll
        for (int ni = 0; ni < 4; ++ni) {
#pragma unroll
            for (int r = 0; r < 4; ++r) {
                int m = bm + wm + mi * 16 + fq * 4 + r;
                int n = bn + wn + ni * 16 + fr;
                float v = acc[mi][ni][r];
                if (n < N_real) {
                    v += bias[n];
                    if (relu) v = fmaxf(v, 0.f);
                    if (res) {
                        if (rbf)
                            v += __bfloat162float(
                                ((const __hip_bfloat16*)res)[(size_t)m * res_ld + n]);
                        else
                            v += ((const float*)res)[(size_t)m * res_ld + n];
                    }
                } else {
                    v = 0.f;
                }
                if (gate) {
                    ((float*)Cout)[(size_t)m * 512 + ((n & 127) << 2)
                                   + ((n >> 7) & 3) + (size_t)(n >> 9) * half_stride] = v;
                } else if (cmp) {
                    if (n < N_real)
                        ((float*)Cout)[(size_t)m * N_real + n] = v;
                } else if (obf) {
                    ((__hip_bfloat16*)Cout)[(size_t)m * Np + n] = __float2bfloat16(v);
                } else {
                    ((float*)Cout)[(size_t)m * Np + n] = v;
                }
            }
        }
    }
}

// ---------------------------------------------------------------------------
// Batched MFMA LSTM recurrence, 1024 threads (16 waves = 4/SIMD).
// Gate pre-activations arrive PRE-SCALED for exp2: i,f,o by -log2e, g by
// +2*log2e (folded into Wih/Whh/bias at cast time). Gate math uses
// 5 raw v_exp_f32 + 3 v_rcp per h (shared denominators).
__global__ __launch_bounds__(1024, 4) void lstm_mfma_kernel(
    const float* __restrict__ pre_f, const float* __restrict__ pre_b,
    const __hip_bfloat16* __restrict__ whh_f,
    const __hip_bfloat16* __restrict__ whh_b,
    void* __restrict__ out, int out_bf16)   // out: (B,S,2*LH)
{
    const int dir = blockIdx.x >> 1;
    const int s0  = (blockIdx.x & 1) * 16;
    const float* pre = dir ? pre_b : pre_f;
    const __hip_bfloat16* whh = dir ? whh_b : whh_f;

    const int tid  = threadIdx.x;
    const int w16  = tid >> 6;
    const int grp  = w16 >> 3;
    const int w8   = w16 & 7;
    const int lane = tid & 63;
    const int l15  = lane & 15;
    const int q    = lane >> 4;
    const int col  = 16 * w8 + l15;
    const int r0   = grp * 2;

    short8 bf[4][4];
#pragma unroll
    for (int t = 0; t < 4; ++t) {
        const __hip_bfloat16* wrow = whh + (size_t)(t * 128 + col) * LH;
#pragma unroll
        for (int kt = 0; kt < 4; ++kt)
            bf[t][kt] = *(const short8*)(wrow + kt * 32 + q * 8);
    }

    __shared__ __hip_bfloat16 h_lds[2][16][136];
    for (int i = tid; i < 2 * 16 * 136; i += 1024)
        ((__hip_bfloat16*)h_lds)[i] = __float2bfloat16(0.f);

    float c0 = 0.f, c1 = 0.f;

    const float* pp0 = pre + ((size_t)(s0 + 4 * q + r0    ) * S + (dir ? (S - 1) : 0)) * G4 + col * 4;
    const float* pp1 = pre + ((size_t)(s0 + 4 * q + r0 + 1) * S + (dir ? (S - 1) : 0)) * G4 + col * 4;
    const int stepoff = dir ? -G4 : G4;

    float4 pc0 = *(const float4*)pp0;
    float4 pc1 = *(const float4*)pp1;

    barrier_lds();
    int p = 0;

    for (int step = 0; step < S; ++step) {
        float4 pn0 = make_float4(0.f, 0.f, 0.f, 0.f);
        float4 pn1 = pn0;
        if (step + 1 < S) {
            pp0 += stepoff; pp1 += stepoff;
            pn0 = *(const float4*)pp0;
            pn1 = *(const float4*)pp1;
        }

        short8 af[4];
#pragma unroll
        for (int kt = 0; kt < 4; ++kt)
            af[kt] = *(const short8*)&h_lds[p][l15][kt * 32 + q * 8];

        f32x4 acc[4];
#pragma unroll
        for (int t = 0; t < 4; ++t) {
            acc[t] = (f32x4){0.f, 0.f, 0.f, 0.f};
#pragma unroll
            for (int kt = 0; kt < 4; ++kt)
                acc[t] = __builtin_amdgcn_mfma_f32_16x16x32_bf16(
                    af[kt], bf[t][kt], acc[t], 0, 0, 0);
        }

        float a0[4], a1[4];
#pragma unroll
        for (int t = 0; t < 4; ++t) {
            a0[t] = grp ? acc[t][2] : acc[t][0];
            a1[t] = grp ? acc[t][3] : acc[t][1];
        }

        const int tcur = dir ? (S - 1 - step) : step;

        // h0 ---------------------------------------------------------------
        float Ei = e2(a0[0] + pc0.x);                 // e^{-i}
        float Ef = e2(a0[1] + pc0.y);                 // e^{-f}
        float Eg = e2(fminf(a0[2] + pc0.z, 80.f));    // e^{2g}
        float Eo = e2(a0[3] + pc0.w);                 // e^{-o}
        float T  = (Eg - 1.f) * frcp((1.f + Ei) * (Eg + 1.f));  // sig(i)tanh(g)
        c0 = fmaf(c0, frcp(1.f + Ef), T);
        float E2 = e2(fminf(c0 * (2.f * L2E), 80.f)); // e^{2c}
        float h0 = (E2 - 1.f) * frcp((1.f + Eo) * (E2 + 1.f));  // sig(o)tanh(c)

        // h1 ---------------------------------------------------------------
        Ei = e2(a1[0] + pc1.x);
        Ef = e2(a1[1] + pc1.y);
        Eg = e2(fminf(a1[2] + pc1.z, 80.f));
        Eo = e2(a1[3] + pc1.w);
        T  = (Eg - 1.f) * frcp((1.f + Ei) * (Eg + 1.f));
        c1 = fmaf(c1, frcp(1.f + Ef), T);
        E2 = e2(fminf(c1 * (2.f * L2E), 80.f));
        float h1 = (E2 - 1.f) * frcp((1.f + Eo) * (E2 + 1.f));

        __hip_bfloat16 hb0 = __float2bfloat16(h0);
        __hip_bfloat16 hb1 = __float2bfloat16(h1);
        h_lds[p ^ 1][4 * q + r0    ][col] = hb0;
        h_lds[p ^ 1][4 * q + r0 + 1][col] = hb1;

        size_t tok0 = (size_t)(s0 + 4 * q + r0    ) * S + tcur;
        size_t tok1 = (size_t)(s0 + 4 * q + r0 + 1) * S + tcur;
        if (out_bf16) {
            ((__hip_bfloat16*)out)[tok0 * 256 + dir * 128 + col] = hb0;
            ((__hip_bfloat16*)out)[tok1 * 256 + dir * 128 + col] = hb1;
        } else {
            ((float*)out)[tok0 * 256 + dir * 128 + col] = h0;
            ((float*)out)[tok1 * 256 + dir * 128 + col] = h1;
        }
        barrier_lds();
        p ^= 1;
        pc0 = pn0; pc1 = pn1;
    }
}

// ---------------------------------------------------------------------------
// CRF NLL per sample (em/mask prefetched one step ahead)
__global__ __launch_bounds__(64) void crf_kernel(
    const float* __restrict__ em, const int* __restrict__ labels,
    const int* __restrict__ mask, const float* __restrict__ trans,
    float* __restrict__ nll)
{
    int b = blockIdx.x, tid = threadIdx.x;
    __shared__ float tr[NT * NT];
    __shared__ float alpha[NT];
    __shared__ float red[64];
    __shared__ float gold_s;

    for (int i = tid; i < NT * NT; i += 64) tr[i] = trans[i];
    __syncthreads();

    float emit = 0.f, pair = 0.f, lenf = 0.f;
    for (int s = tid; s < S; s += 64) {
        int lab = labels[b * S + s];
        float mf = (float)mask[b * S + s];
        emit += em[(size_t)(b * S + s) * NT + lab] * mf;
        lenf += mf;
        if (s >= 1) {
            int lp = labels[b * S + s - 1];
            pair += tr[lp * NT + lab] * mf;
        }
    }
    red[tid] = emit; __syncthreads();
    for (int st = 32; st > 0; st >>= 1) { if (tid < st) red[tid] += red[tid + st]; __syncthreads(); }
    float emit_tot = red[0]; __syncthreads();
    red[tid] = pair; __syncthreads();
    for (int st = 32; st > 0; st >>= 1) { if (tid < st) red[tid] += red[tid + st]; __syncthreads(); }
    float pair_tot = red[0]; __syncthreads();
    red[tid] = lenf; __syncthreads();
    for (int st = 32; st > 0; st >>= 1) { if (tid < st) red[tid] += red[tid + st]; __syncthreads(); }
    float len_tot = red[0]; __syncthreads();

    if (tid == 0) {
        int len_i = (int)(len_tot + 0.5f);
        int last = labels[b * S + len_i - 1];
        gold_s = tr[START_TAG * NT + labels[b * S]] + emit_tot + pair_tot
               + tr[last * NT + END_TAG];
    }
    if (tid < NT) alpha[tid] = tr[START_TAG * NT + tid] + em[(size_t)(b * S) * NT + tid];
    __syncthreads();

    float ecur = (tid < NT) ? em[(size_t)(b * S + 1) * NT + tid] : 0.f;
    int   mcur = mask[b * S + 1];

    for (int t = 1; t < S; ++t) {
        // prefetch t+1
        float enxt = 0.f; int mnxt = 0;
        if (t + 1 < S) {
            if (tid < NT) enxt = em[(size_t)(b * S + t + 1) * NT + tid];
            mnxt = mask[b * S + t + 1];
        }
        float newv = 0.f;
        if (tid < NT) {
            float vals[NT];
            float m = -1e30f;
#pragma unroll
            for (int i2 = 0; i2 < NT; ++i2) {
                float v = alpha[i2] + tr[i2 * NT + tid];
                vals[i2] = v;
                m = fmaxf(m, v);
            }
            float ssum = 0.f;
#pragma unroll
            for (int i2 = 0; i2 < NT; ++i2) ssum += __expf(vals[i2] - m);
            newv = m + __logf(ssum) + ecur;
            if (!(mcur > 0)) newv = alpha[tid];
        }
        __syncthreads();
        if (tid < NT) alpha[tid] = newv;
        __syncthreads();
        ecur = enxt; mcur = mnxt;
    }

    if (tid < NT) red[tid] = alpha[tid] + tr[tid * NT + END_TAG];
    __syncthreads();
    if (tid == 0) {
        float m = -1e30f;
        for (int j = 0; j < NT; ++j) m = fmaxf(m, red[j]);
        float ssum = 0.f;
        for (int j = 0; j < NT; ++j) ssum += __expf(red[j] - m);
        float logZ = m + __logf(ssum);
        nll[b] = logZ - gold_s;
    }
}

__global__ void mean_kernel(const float* __restrict__ nll, float* __restrict__ out)
{
    if (threadIdx.x == 0) {
        float s = 0.f;
        for (int i = 0; i < B; ++i) s += nll[i];
        out[0] = s / (float)B;
    }
}

// ---------------------------------------------------------------------------
extern "C" void kernel_launch(void* const* d_in, const int* in_sizes, int n_in,
                              void* d_out, int out_size, void* d_ws, size_t ws_size,
                              hipStream_t stream)
{
    const float* in_emb = (const float*)d_in[0];
    const int*   mask   = (const int*)d_in[1];
    const int*   labels = (const int*)d_in[2];
    const float* kg_W1  = (const float*)d_in[3];
    const float* kg_b1  = (const float*)d_in[4];
    const float* ln_g   = (const float*)d_in[5];
    const float* ln_b   = (const float*)d_in[6];
    const float* kg_W2  = (const float*)d_in[7];
    const float* kg_b2  = (const float*)d_in[8];
    const float* ff_W1  = (const float*)d_in[9];
    const float* ff_b1  = (const float*)d_in[10];
    const float* ff_W2  = (const float*)d_in[11];
    const float* ff_b2  = (const float*)d_in[12];
    const float* Wih0f  = (const float*)d_in[13];
    const float* Whh0f  = (const float*)d_in[14];
    const float* b0f    = (const float*)d_in[15];
    const float* Wih0b  = (const float*)d_in[16];
    const float* Whh0b  = (const float*)d_in[17];
    const float* b0b    = (const float*)d_in[18];
    const float* Wih1f  = (const float*)d_in[19];
    const float* Whh1f  = (const float*)d_in[20];
    const float* b1f    = (const float*)d_in[21];
    const float* Wih1b  = (const float*)d_in[22];
    const float* Whh1b  = (const float*)d_in[23];
    const float* b1b    = (const float*)d_in[24];
    const float* cls_W  = (const float*)d_in[25];
    const float* cls_b  = (const float*)d_in[26];
    const float* trans  = (const float*)d_in[27];
    (void)ws_size; (void)in_sizes; (void)n_in; (void)out_size;

    // ---- workspace arena ----
    char* wsb = (char*)d_ws;
    size_t o = 0;
    __hip_bfloat16* Ab     = (__hip_bfloat16*)(wsb + o);   size_t ab_off = o; o += (size_t)M_TOK * DP * 2;
    char*           big    = wsb + o;                      o += (size_t)M_TOK * FF * 2;
    __hip_bfloat16* xb     = (__hip_bfloat16*)(wsb + o);   o += (size_t)M_TOK * DP * 2;
    __hip_bfloat16* Wbff1  = (__hip_bfloat16*)(wsb + o);   o += (size_t)FF * DP * 2;
    __hip_bfloat16* Wbff2  = (__hip_bfloat16*)(wsb + o);   o += (size_t)DP * FF * 2;
    __hip_bfloat16* Wb0    = (__hip_bfloat16*)(wsb + o);   o += (size_t)1024 * DP * 2;   // stacked f|b
    __hip_bfloat16* Wb1    = (__hip_bfloat16*)(wsb + o);   o += (size_t)1024 * 256 * 2;  // stacked f|b
    __hip_bfloat16* Whb0f  = (__hip_bfloat16*)(wsb + o);   o += (size_t)G4 * LH * 2;
    __hip_bfloat16* Whb0b  = (__hip_bfloat16*)(wsb + o);   o += (size_t)G4 * LH * 2;
    __hip_bfloat16* Whb1f  = (__hip_bfloat16*)(wsb + o);   o += (size_t)G4 * LH * 2;
    __hip_bfloat16* Whb1b  = (__hip_bfloat16*)(wsb + o);   o += (size_t)G4 * LH * 2;
    __hip_bfloat16* Wbkg1  = (__hip_bfloat16*)(wsb + o);   o += (size_t)H * KGP * 2;
    __hip_bfloat16* Wbcls  = (__hip_bfloat16*)(wsb + o);   o += (size_t)128 * 256 * 2;
    float*          sb0    = (float*)(wsb + o);            o += 1024 * 4;
    float*          sb1    = (float*)(wsb + o);            o += 1024 * 4;
    float*          scores = (float*)(wsb + o);            o += (size_t)M_TOK * 4;
    float*          attw   = (float*)(wsb + o);            o += (size_t)M_TOK * 4;
    float*          emis   = (float*)(wsb + o);            o += (size_t)M_TOK * NT * 4;
    float*          nll    = (float*)(wsb + o);            o += B * 4;
    // big region reuse timeline:
    __hip_bfloat16* h16   = (__hip_bfloat16*)(big + 0);                // kg proj out (12.6MB)
    __hip_bfloat16* Akg   = (__hip_bfloat16*)(big + 33554432);         // kg bf16 in
    __hip_bfloat16* ff1b  = (__hip_bfloat16*)big;                      // FF1 out
    float*          pre0f = (float*)(big + 0);                         // after FF2
    float*          pre0b = (float*)(big + 16777216);
    __hip_bfloat16* x1b   = (__hip_bfloat16*)(big + 33554432);         // LSTM0 out
    float*          pre1f = (float*)(big + 0);                         // after LSTM0
    float*          pre1b = (float*)(big + 16777216);
    __hip_bfloat16* x2b   = (__hip_bfloat16*)(wsb + ab_off);           // LSTM1 out (reuse Ab)
    const size_t HALF_STRIDE = 4194304;                                // floats pre0f->pre0b

    // ---- weight prep ----
    castpad2d_kernel<<<(FF * DP + 255) / 256, 256, 0, stream>>>(ff_W1, Wbff1, FF, D,  FF, DP, 0);
    castpad2d_kernel<<<(DP * FF + 255) / 256, 256, 0, stream>>>(ff_W2, Wbff2, D,  FF, DP, FF, 0);
    // stacked + gate-scaled LSTM input weights
    castpad2d_kernel<<<(G4 * DP + 255) / 256, 256, 0, stream>>>(Wih0f, Wb0,            G4, D, G4, DP, 1);
    castpad2d_kernel<<<(G4 * DP + 255) / 256, 256, 0, stream>>>(Wih0b, Wb0 + 512 * DP, G4, D, G4, DP, 1);
    castpad2d_kernel<<<(G4 * 256 + 255) / 256, 256, 0, stream>>>(Wih1f, Wb1,             G4, 256, G4, 256, 1);
    castpad2d_kernel<<<(G4 * 256 + 255) / 256, 256, 0, stream>>>(Wih1b, Wb1 + 512 * 256, G4, 256, G4, 256, 1);
    prep_misc_kernel<<<(PREP_TOTAL + 255) / 256, 256, 0, stream>>>(
        Whh0f, Whh0b, Whh1f, Whh1b, b0f, b0b, b1f, b1b, cls_W, kg_W1,
        Whb0f, Whb0b, Whb1f, Whb1b, sb0, sb1, Wbcls, Wbkg1);

    // ---- attention front-end ----
    castpad_kg_kernel<<<(M_TOK * KGP + 255) / 256, 256, 0, stream>>>(in_emb, Akg);
    mfma_gemm<<<dim3(H / 128, M_TOK / 128), 256, 0, stream>>>(
        Akg, Wbkg1, kg_b1, nullptr, 0, 0, h16, H, KGP, H, 2);
    ln_score_kernel<<<M_TOK / 4, 256, 0, stream>>>(
        h16, ln_g, ln_b, kg_W2, kg_b2, scores);
    softmax_kernel<<<B, 256, 0, stream>>>(scores, attw);
    combine2_kernel<<<(M_TOK * DP + 255) / 256, 256, 0, stream>>>(in_emb, attw, Ab);

    // ---- FF block ----
    mfma_gemm<<<dim3(FF / 128, M_TOK / 128), 256, 0, stream>>>(
        Ab, Wbff1, ff_b1, nullptr, 0, 0, ff1b, FF, DP, FF, 1 | 2);
    mfma_gemm<<<dim3(DP / 128, M_TOK / 128), 256, 0, stream>>>(
        ff1b, Wbff2, ff_b2, Ab, DP, 0, xb, DP, FF, D, 2 | 16);

    // ---- LSTM layer 0 (stacked fwd+bwd pre GEMM, gate-interleaved) ----
    mfma_gemm<<<dim3(1024 / 128, M_TOK / 128), 256, 0, stream>>>(
        xb, Wb0, sb0, nullptr, 0, HALF_STRIDE, pre0f, 1024, DP, 1024, 4);
    lstm_mfma_kernel<<<4, 1024, 0, stream>>>(pre0f, pre0b, Whb0f, Whb0b, x1b, 1);

    // ---- LSTM layer 1 ----
    mfma_gemm<<<dim3(1024 / 128, M_TOK / 128), 256, 0, stream>>>(
        x1b, Wb1, sb1, nullptr, 0, HALF_STRIDE, pre1f, 1024, 256, 1024, 4);
    lstm_mfma_kernel<<<4, 1024, 0, stream>>>(pre1f, pre1b, Whb1f, Whb1b, x2b, 1);

    // ---- emissions + CRF + mean ----
    mfma_gemm<<<dim3(1, M_TOK / 128), 256, 0, stream>>>(
        x2b, Wbcls, cls_b, nullptr, 0, 0, emis, 128, 256, NT, 8);
    crf_kernel<<<B, 64, 0, stream>>>(emis, labels, mask, trans, nll);
    mean_kernel<<<1, 64, 0, stream>>>(nll, (float*)d_out);
}